// Round 9
// baseline (952.522 us; speedup 1.0000x reference)
//
#include <hip/hip_runtime.h>
#include <stdint.h>

#define T_DIM 512
#define B_DIM 256
#define OBS_DIM 128
#define H_DIM 256
#define TB (T_DIM * B_DIM)

typedef _Float16 f16;
typedef __attribute__((ext_vector_type(8))) _Float16 f16x8;
typedef __attribute__((ext_vector_type(4))) float f32x4;

union H2U { f16 h[2]; uint32_t u; };

__device__ __forceinline__ f32x4 fz4() { f32x4 v; v[0]=0.f; v[1]=0.f; v[2]=0.f; v[3]=0.f; return v; }
__device__ __forceinline__ float sigm(float x) {
  float e = __expf(-x);
  return __builtin_amdgcn_rcpf(1.f + e);
}
__device__ __forceinline__ float tanh_f(float x) {
  float e = __expf(-2.f * x);
  return (1.f - e) * __builtin_amdgcn_rcpf(1.f + e);
}

// ---------------------------------------------------------------------------
// K0: weights -> f16. encW 32768 | Wih 196608 | head 8192 (rows0-15 pol,16 val)
// ---------------------------------------------------------------------------
__global__ void k_prep(const float* __restrict__ encW, const float* __restrict__ Wih,
                       const float* __restrict__ polW, const float* __restrict__ valW,
                       f16* __restrict__ encW_h, f16* __restrict__ Wih_h,
                       f16* __restrict__ headW_h) {
  int e = blockIdx.x * 256 + threadIdx.x;
  if (e < 32768) { encW_h[e] = (f16)encW[e]; return; }
  e -= 32768;
  if (e < 196608) { Wih_h[e] = (f16)Wih[e]; return; }
  e -= 196608;
  if (e < 8192) {
    int r = e >> 8, c = e & 255;
    float v = (r < 16) ? polW[r * 256 + c] : (r == 16 ? valW[c] : 0.f);
    headW_h[e] = (f16)v;
  }
}

// ---------------------------------------------------------------------------
// K1: x = tanh(obs @ enc_W^T + enc_b) -> f16 into xgi. M-tile 128, grid 1024.
// ---------------------------------------------------------------------------
__global__ __launch_bounds__(512) void k_enc(const float* __restrict__ obs,
                                             const f16* __restrict__ encW_h,
                                             const float* __restrict__ enc_b,
                                             f16* __restrict__ xgi) {
  __shared__ f16 lA[128 * 64];  // 16KB [128 rows][64 k] swizzled
  __shared__ f16 lB[256 * 64];  // 32KB [256 n][64 k] swizzled
  const int tid = threadIdx.x, lane = tid & 63, w = tid >> 6;
  const int m0 = blockIdx.x * 128;
  f32x4 acc[16];
#pragma unroll
  for (int i = 0; i < 16; i++) acc[i] = fz4();

  for (int kc = 0; kc < 2; kc++) {
    const int k0c = kc * 64;
#pragma unroll
    for (int i = 0; i < 4; i++) {
      int c = tid + i * 512;
      int r = c >> 4, kk = (c & 15) * 4;
      float4 v = *(const float4*)(obs + (size_t)(m0 + r) * OBS_DIM + k0c + kk);
      H2U a, b;
      a.h[0] = (f16)v.x; a.h[1] = (f16)v.y; b.h[0] = (f16)v.z; b.h[1] = (f16)v.w;
      uint32_t off = ((uint32_t)(r * 128 + kk * 2)) ^ (((uint32_t)(r & 7)) << 4);
      uint2 p; p.x = a.u; p.y = b.u;
      *(uint2*)((char*)lA + off) = p;
    }
#pragma unroll
    for (int i = 0; i < 4; i++) {
      int c = tid + i * 512;
      int r = c >> 3, kk = (c & 7) * 8;
      f16x8 v = *(const f16x8*)(encW_h + (size_t)r * OBS_DIM + k0c + kk);
      uint32_t off = ((uint32_t)(r * 128 + kk * 2)) ^ (((uint32_t)(r & 7)) << 4);
      *(f16x8*)((char*)lB + off) = v;
    }
    __syncthreads();
#pragma unroll
    for (int ks = 0; ks < 2; ks++) {
      const int ar = w * 16 + (lane & 15);
      const int kofs = (ks * 32 + ((lane >> 4) << 3)) * 2;
      uint32_t aoff = ((uint32_t)(ar * 128 + kofs)) ^ (((uint32_t)(ar & 7)) << 4);
      f16x8 af = *(const f16x8*)((char*)lA + aoff);
#pragma unroll
      for (int i = 0; i < 16; i++) {
        const int br = i * 16 + (lane & 15);
        uint32_t boff = ((uint32_t)(br * 128 + kofs)) ^ (((uint32_t)(br & 7)) << 4);
        f16x8 bfr = *(const f16x8*)((char*)lB + boff);
        acc[i] = __builtin_amdgcn_mfma_f32_16x16x32_f16(af, bfr, acc[i], 0, 0, 0);
      }
    }
    __syncthreads();
  }
  const int mrow = m0 + w * 16 + ((lane >> 4) << 2);
#pragma unroll
  for (int i = 0; i < 16; i++) {
    const int col = i * 16 + (lane & 15);
    const float bb = enc_b[col];
#pragma unroll
    for (int r = 0; r < 4; r++) {
      float s = acc[i][r] + bb;
      xgi[(size_t)(mrow + r) * H_DIM + col] = (f16)tanh_f(s);
    }
  }
}

// ---------------------------------------------------------------------------
// K2: all 3 gates fused: gi = x @ W_ih^T + bias. M-tile 64, N=768, grid 2048.
// r,z -> gi_rz f16 [TB][256][2] INTERLEAVED; n -> xgi [TB][256].
// ---------------------------------------------------------------------------
__global__ __launch_bounds__(512) void k_gi3(const f16* __restrict__ xgi_r,
                                             const f16* __restrict__ Wih_h,
                                             const float* __restrict__ b_ih,
                                             const float* __restrict__ b_hh,
                                             f16* __restrict__ gi_rz,
                                             f16* __restrict__ xgi_w) {
  __shared__ f16 lA[64 * 64];    // 8KB
  __shared__ f16 lB[768 * 64];   // 96KB
  const int tid = threadIdx.x, lane = tid & 63, w = tid >> 6;
  const int m0 = blockIdx.x * 64;
  const int mstrip = w >> 1, nh = w & 1;
  f32x4 acc[24];
#pragma unroll
  for (int i = 0; i < 24; i++) acc[i] = fz4();

  for (int kc = 0; kc < 4; kc++) {
    const int k0c = kc * 64;
    {
      int r = tid >> 3, kk = (tid & 7) * 8;
      f16x8 v = *(const f16x8*)(xgi_r + (size_t)(m0 + r) * H_DIM + k0c + kk);
      uint32_t off = ((uint32_t)(r * 128 + kk * 2)) ^ (((uint32_t)(r & 7)) << 4);
      *(f16x8*)((char*)lA + off) = v;
    }
#pragma unroll
    for (int i = 0; i < 12; i++) {
      int c = tid + i * 512;
      int r = c >> 3, kk = (c & 7) * 8;
      f16x8 v = *(const f16x8*)(Wih_h + (size_t)r * H_DIM + k0c + kk);
      uint32_t off = ((uint32_t)(r * 128 + kk * 2)) ^ (((uint32_t)(r & 7)) << 4);
      *(f16x8*)((char*)lB + off) = v;
    }
    __syncthreads();
#pragma unroll
    for (int ks = 0; ks < 2; ks++) {
      const int ar = mstrip * 16 + (lane & 15);
      const int kofs = (ks * 32 + ((lane >> 4) << 3)) * 2;
      uint32_t aoff = ((uint32_t)(ar * 128 + kofs)) ^ (((uint32_t)(ar & 7)) << 4);
      f16x8 af = *(const f16x8*)((char*)lA + aoff);
#pragma unroll
      for (int i = 0; i < 24; i++) {
        const int br = nh * 384 + i * 16 + (lane & 15);
        uint32_t boff = ((uint32_t)(br * 128 + kofs)) ^ (((uint32_t)(br & 7)) << 4);
        f16x8 bfr = *(const f16x8*)((char*)lB + boff);
        acc[i] = __builtin_amdgcn_mfma_f32_16x16x32_f16(af, bfr, acc[i], 0, 0, 0);
      }
    }
    __syncthreads();
  }
  const int mrow = m0 + mstrip * 16 + ((lane >> 4) << 2);
#pragma unroll
  for (int i = 0; i < 24; i++) {
    const int col = nh * 384 + i * 16 + (lane & 15);
    float bb = b_ih[col];
    if (col < 512) bb += b_hh[col];
#pragma unroll
    for (int r = 0; r < 4; r++) {
      float s = acc[i][r] + bb;
      size_t tb = (size_t)(mrow + r);
      if (col < 512) gi_rz[tb * 512 + (size_t)((col & 255) * 2 + (col >> 8))] = (f16)s;
      else           xgi_w[tb * 256 + (col - 512)] = (f16)s;
    }
  }
}

// ---------------------------------------------------------------------------
// K3: GRU scan v9. grid(128) x block 512 (8 waves, 2/SIMD), WG owns 2 batch
// rows. KEY CHANGE vs v5/v7: gates computed IN the accumulator's own lanes
// (C-frag layout: lane l<16 holds rows 0,1 of col l for all 6 N-tiles) ->
// the gh LDS write/fence/read round-trip is DELETED. Each lane<16 computes
// 4 h-outputs (2 rows x 2 col16s). h_l is 2 rows (A-rows 2-15 feed unread
// D rows; lanes re-read row lane&1 -> broadcast). One lgkm+s_barrier/step.
// ---------------------------------------------------------------------------
__global__ __launch_bounds__(512, 2) void k_scan(const float* __restrict__ Whh,
                                                 const float* __restrict__ b_hh,
                                                 const float* __restrict__ done,
                                                 const uint32_t* __restrict__ gi_rz,
                                                 f16* xgi) {
  __shared__ f16 h_l[2][2][264];         // ~2.1KB [buf][row][k]
  __shared__ float done_l[T_DIM][2];     // 4KB
  __shared__ f16 wb_l[8 * 12 * 64 * 8];  // 96KB [w][i2j][lane][8] ks 6,7 frags
  const int tid = threadIdx.x, lane = tid & 63, w = tid >> 6;
  const int b0 = blockIdx.x * 2;

  for (int i = tid; i < 2 * 2 * 264; i += 512) ((f16*)h_l)[i] = (f16)0.f;
  {
    float2 dv = *(const float2*)(done + (size_t)tid * B_DIM + b0);
    done_l[tid][0] = dv.x; done_l[tid][1] = dv.y;
  }

  // W_hh -> f16 B-frags: ks 0-5 in regs, ks 6-7 into LDS (lane-contig)
  f16x8 wf[6][6];
#pragma unroll
  for (int g = 0; g < 3; g++) {
#pragma unroll
    for (int hh = 0; hh < 2; hh++) {
      const int i6 = g * 2 + hh;
      const int rowW = g * 256 + w * 32 + hh * 16 + (lane & 15);
      const float* wrow = Whh + (size_t)rowW * H_DIM;
#pragma unroll
      for (int ks = 0; ks < 8; ks++) {
        const int k0 = ks * 32 + ((lane >> 4) << 3);
        float4 a = *(const float4*)(wrow + k0);
        float4 b = *(const float4*)(wrow + k0 + 4);
        f16x8 f;
        f[0] = (f16)a.x; f[1] = (f16)a.y; f[2] = (f16)a.z; f[3] = (f16)a.w;
        f[4] = (f16)b.x; f[5] = (f16)b.y; f[6] = (f16)b.z; f[7] = (f16)b.w;
        if (ks < 6) wf[i6][ks] = f;
        else *(f16x8*)&wb_l[((w * 12 + i6 * 2 + (ks - 6)) * 64 + lane) * 8] = f;
      }
    }
  }
  // C-in seeds: zero for r,z (bias folded in gi); b_hh_n splat for n tiles.
  // Seed value must be b_hh[512 + col] with col = lane's C-column (lane&15).
  f32x4 zs = fz4();
  f32x4 ns0, ns1;
  {
    const float bv0 = b_hh[512 + w * 32 + (lane & 15)];
    const float bv1 = b_hh[512 + w * 32 + 16 + (lane & 15)];
    ns0[0] = bv0; ns0[1] = bv0; ns0[2] = bv0; ns0[3] = bv0;
    ns1[0] = bv1; ns1[1] = bv1; ns1[2] = bv1; ns1[3] = bv1;
  }

  // A-frag base: broadcast rows 0/1 (A rows 2-15 only affect unread D rows)
  const int koff = (lane >> 4) << 3;
  const f16* hA = &h_l[0][lane & 1][koff];
  const f16* hB = &h_l[1][lane & 1][koff];
  const f16* wrd = &wb_l[(w * 12 * 64 + lane) * 8];

  // phase-B: lanes 0-15 own col0 = 32w+l (tiles cc=0) and col1 = col0+16
  const bool doB = (lane < 16);
  const int l = lane & 15;
  const int col0 = w * 32 + l, col1 = col0 + 16;
  const uint32_t* prz = gi_rz + (size_t)b0 * 256;  // + t*65536 + row*256 + col
  f16* pgn = xgi + (size_t)b0 * 256;
  // gi prefetch for t=0: [cc][row]
  uint32_t rzN[2][2]; f16 gnN[2][2];
  if (doB) {
    rzN[0][0] = prz[col0];       rzN[1][0] = prz[col1];
    rzN[0][1] = prz[256 + col0]; rzN[1][1] = prz[256 + col1];
    gnN[0][0] = pgn[col0];       gnN[1][0] = pgn[col1];
    gnN[0][1] = pgn[256 + col0]; gnN[1][1] = pgn[256 + col1];
  }
  float hp[2][2];
  hp[0][0] = 0.f; hp[0][1] = 0.f; hp[1][0] = 0.f; hp[1][1] = 0.f;
  __syncthreads();

  for (int t = 0; t < T_DIM; t++) {
    // consume current gi, issue prefetch for t+1
    uint32_t rzC[2][2]; f16 gnC[2][2];
#pragma unroll
    for (int cc = 0; cc < 2; cc++)
#pragma unroll
      for (int r = 0; r < 2; r++) { rzC[cc][r] = rzN[cc][r]; gnC[cc][r] = gnN[cc][r]; }
    if (doB && t != T_DIM - 1) {
      const uint32_t* p1 = prz + (size_t)(t + 1) * 65536;
      const f16* g1 = pgn + (size_t)(t + 1) * 65536;
      rzN[0][0] = p1[col0];       rzN[1][0] = p1[col1];
      rzN[0][1] = p1[256 + col0]; rzN[1][1] = p1[256 + col1];
      gnN[0][0] = g1[col0];       gnN[1][0] = g1[col1];
      gnN[0][1] = g1[256 + col0]; gnN[1][1] = g1[256 + col1];
    }
    const int cur = t & 1;
    const f16* hrd = (t & 1) ? hB : hA;

    // phase A: gh = h @ W_hh^T (48 MFMA, A-operand broadcast-read)
    f32x4 acc[6];
    __builtin_amdgcn_s_setprio(1);
    {
      const f16x8 af0 = *(const f16x8*)&hrd[0];
      acc[0] = __builtin_amdgcn_mfma_f32_16x16x32_f16(af0, wf[0][0], zs, 0, 0, 0);
      acc[1] = __builtin_amdgcn_mfma_f32_16x16x32_f16(af0, wf[1][0], zs, 0, 0, 0);
      acc[2] = __builtin_amdgcn_mfma_f32_16x16x32_f16(af0, wf[2][0], zs, 0, 0, 0);
      acc[3] = __builtin_amdgcn_mfma_f32_16x16x32_f16(af0, wf[3][0], zs, 0, 0, 0);
      acc[4] = __builtin_amdgcn_mfma_f32_16x16x32_f16(af0, wf[4][0], ns0, 0, 0, 0);
      acc[5] = __builtin_amdgcn_mfma_f32_16x16x32_f16(af0, wf[5][0], ns1, 0, 0, 0);
    }
#pragma unroll
    for (int ks = 1; ks < 6; ks++) {
      const f16x8 af = *(const f16x8*)&hrd[ks * 32];
#pragma unroll
      for (int i = 0; i < 6; i++)
        acc[i] = __builtin_amdgcn_mfma_f32_16x16x32_f16(af, wf[i][ks], acc[i], 0, 0, 0);
    }
#pragma unroll
    for (int j = 0; j < 2; j++) {
      const f16x8 af = *(const f16x8*)&hrd[(6 + j) * 32];
#pragma unroll
      for (int i = 0; i < 6; i++) {
        const f16x8 bf = *(const f16x8*)&wrd[(i * 2 + j) * 512];
        acc[i] = __builtin_amdgcn_mfma_f32_16x16x32_f16(af, bf, acc[i], 0, 0, 0);
      }
    }
    __builtin_amdgcn_s_setprio(0);

    // phase B: gates in the accumulator's own lanes. Lane l<16 holds
    // (row 0,1) x (col0: tiles 0/2/4, col1: tiles 1/3/5) in acc regs 0,1.
    if (doB) {
      f16* po = pgn + (size_t)t * 65536;
#pragma unroll
      for (int cc = 0; cc < 2; cc++) {
        const int cg = cc ? col1 : col0;
#pragma unroll
        for (int r = 0; r < 2; r++) {
          H2U u; u.u = rzC[cc][r];
          const float rr = sigm((float)u.h[0] + acc[0 + cc][r]);
          const float zz = sigm((float)u.h[1] + acc[2 + cc][r]);
          const float nn = tanh_f((float)gnC[cc][r] + rr * acc[4 + cc][r]);
          const float ho = nn + zz * (hp[cc][r] - nn);
          po[r * 256 + cg] = (f16)ho;                 // outs (same slot as gi_n)
          const float dn = done_l[t][r];              // masks h going into t+1
          const float hn = (dn != 0.f) ? 0.f : ho;
          hp[cc][r] = hn;
          h_l[cur ^ 1][r][cg] = (f16)hn;
        }
      }
    }

    // single raw barrier: drain LDS writes, then s_barrier (no vmcnt drain).
    __builtin_amdgcn_sched_barrier(0);
    asm volatile("s_waitcnt lgkmcnt(0)" ::: "memory");
    __builtin_amdgcn_s_barrier();
    __builtin_amdgcn_sched_barrier(0);
  }
}

// ---------------------------------------------------------------------------
// K4: heads. M-tile 64, N=32 (16 pol + 1 val + pad), grid 2048, block 256.
// ---------------------------------------------------------------------------
__global__ __launch_bounds__(256) void k_heads(const f16* __restrict__ outs,
                                               const f16* __restrict__ headW_h,
                                               const float* __restrict__ pol_b,
                                               const float* __restrict__ val_b,
                                               float* __restrict__ out) {
  __shared__ f16 lA[64 * 256];  // 32KB swizzled
  __shared__ f16 lB[32 * 256];  // 16KB
  const int tid = threadIdx.x, lane = tid & 63, w = tid >> 6;
  const int m0 = blockIdx.x * 64;
#pragma unroll
  for (int i = 0; i < 8; i++) {
    int c = tid + i * 256;
    int r = c >> 5, o = (c & 31) * 8;
    f16x8 v = *(const f16x8*)(outs + (size_t)(m0 + r) * H_DIM + o);
    uint32_t off = ((uint32_t)(r * 512 + o * 2)) ^ (((uint32_t)(r & 7)) << 4);
    *(f16x8*)((char*)lA + off) = v;
  }
#pragma unroll
  for (int i = 0; i < 4; i++) {
    int c = tid + i * 256;
    int r = c >> 5, o = (c & 31) * 8;
    f16x8 v = *(const f16x8*)(headW_h + (size_t)r * H_DIM + o);
    uint32_t off = ((uint32_t)(r * 512 + o * 2)) ^ (((uint32_t)(r & 7)) << 4);
    *(f16x8*)((char*)lB + off) = v;
  }
  __syncthreads();
  f32x4 acc[2];
  acc[0] = fz4(); acc[1] = fz4();
#pragma unroll
  for (int ks = 0; ks < 8; ks++) {
    const int ar = w * 16 + (lane & 15);
    const int kofs = (ks * 32 + ((lane >> 4) << 3)) * 2;
    uint32_t aoff = ((uint32_t)(ar * 512 + kofs)) ^ (((uint32_t)(ar & 7)) << 4);
    f16x8 af = *(const f16x8*)((char*)lA + aoff);
#pragma unroll
    for (int nt = 0; nt < 2; nt++) {
      const int br = nt * 16 + (lane & 15);
      uint32_t boff = ((uint32_t)(br * 512 + kofs)) ^ (((uint32_t)(br & 7)) << 4);
      f16x8 bfr = *(const f16x8*)((char*)lB + boff);
      acc[nt] = __builtin_amdgcn_mfma_f32_16x16x32_f16(af, bfr, acc[nt], 0, 0, 0);
    }
  }
  const int n = lane & 15;
  const float pb = pol_b[n];
  const float vb = val_b[0];
#pragma unroll
  for (int r = 0; r < 4; r++) {
    const int mrow = m0 + w * 16 + ((lane >> 4) << 2) + r;
    out[(size_t)mrow * 16 + n] = acc[0][r] + pb;
    if (n == 0) out[(size_t)TB * 16 + mrow] = acc[1][r] + vb;
  }
}

// ---------------------------------------------------------------------------
// Workspace layout (192.5 MiB total):
//   [0,128Mi)        gi_rz f16 [TB][256][2]  (r,z interleaved)
//   [128Mi,192Mi)    xgi  f16 [TB][256]  (x -> gi_n -> outs, race-free)
//   [192Mi,+475KB)   encW_h | Wih_h | headW_h
// ---------------------------------------------------------------------------
extern "C" void kernel_launch(void* const* d_in, const int* in_sizes, int n_in,
                              void* d_out, int out_size, void* d_ws, size_t ws_size,
                              hipStream_t stream) {
  (void)in_sizes; (void)n_in; (void)out_size; (void)ws_size;
  const float* obs   = (const float*)d_in[0];
  const float* done  = (const float*)d_in[1];
  const float* encW  = (const float*)d_in[2];
  const float* enc_b = (const float*)d_in[3];
  const float* Wih   = (const float*)d_in[4];
  const float* Whh   = (const float*)d_in[5];
  const float* b_ih  = (const float*)d_in[6];
  const float* b_hh  = (const float*)d_in[7];
  const float* polW  = (const float*)d_in[8];
  const float* pol_b = (const float*)d_in[9];
  const float* valW  = (const float*)d_in[10];
  const float* val_b = (const float*)d_in[11];

  char* ws = (char*)d_ws;
  f16* gi_rz   = (f16*)ws;
  f16* xgi     = (f16*)(ws + (size_t)134217728);
  f16* encW_h  = (f16*)(ws + (size_t)201326592);
  f16* Wih_h   = encW_h + 32768;
  f16* headW_h = Wih_h + 196608;
  float* outp  = (float*)d_out;

  k_prep<<<dim3(928), dim3(256), 0, stream>>>(encW, Wih, polW, valW, encW_h, Wih_h, headW_h);
  k_enc<<<dim3(1024), dim3(512), 0, stream>>>(obs, encW_h, enc_b, xgi);
  k_gi3<<<dim3(2048), dim3(512), 0, stream>>>(xgi, Wih_h, b_ih, b_hh, gi_rz, xgi);
  k_scan<<<dim3(128), dim3(512), 0, stream>>>(Whh, b_hh, done, (const uint32_t*)gi_rz, xgi);
  k_heads<<<dim3(2048), dim3(256), 0, stream>>>(xgi, headW_h, pol_b, val_b, outp);
}

// Round 10
// 781.269 us; speedup vs baseline: 1.2192x; 1.2192x over previous
//
#include <hip/hip_runtime.h>
#include <stdint.h>

#define T_DIM 512
#define B_DIM 256
#define OBS_DIM 128
#define H_DIM 256
#define TB (T_DIM * B_DIM)

typedef _Float16 f16;
typedef __attribute__((ext_vector_type(8))) _Float16 f16x8;
typedef __attribute__((ext_vector_type(4))) float f32x4;

union H2U { f16 h[2]; uint32_t u; };

__device__ __forceinline__ f32x4 fz4() { f32x4 v; v[0]=0.f; v[1]=0.f; v[2]=0.f; v[3]=0.f; return v; }
__device__ __forceinline__ float sigm(float x) {
  float e = __expf(-x);
  return __builtin_amdgcn_rcpf(1.f + e);
}
__device__ __forceinline__ float tanh_f(float x) {
  float e = __expf(-2.f * x);
  return (1.f - e) * __builtin_amdgcn_rcpf(1.f + e);
}

// ---------------------------------------------------------------------------
// K0: weights -> f16. encW 32768 | Wih 196608 | head 8192 (rows0-15 pol,16 val)
// ---------------------------------------------------------------------------
__global__ void k_prep(const float* __restrict__ encW, const float* __restrict__ Wih,
                       const float* __restrict__ polW, const float* __restrict__ valW,
                       f16* __restrict__ encW_h, f16* __restrict__ Wih_h,
                       f16* __restrict__ headW_h) {
  int e = blockIdx.x * 256 + threadIdx.x;
  if (e < 32768) { encW_h[e] = (f16)encW[e]; return; }
  e -= 32768;
  if (e < 196608) { Wih_h[e] = (f16)Wih[e]; return; }
  e -= 196608;
  if (e < 8192) {
    int r = e >> 8, c = e & 255;
    float v = (r < 16) ? polW[r * 256 + c] : (r == 16 ? valW[c] : 0.f);
    headW_h[e] = (f16)v;
  }
}

// ---------------------------------------------------------------------------
// K1: FUSED encoder + gate GEMM. grid 2048 (M-tile 64), block 512 (8 waves).
// Phase E: x-tile = tanh(obs @ enc_W^T + enc_b) computed INTO LDS (never HBM).
// Phase G: gi = x @ W_ih^T + bias, K=256 in 4 chunks.
//   wave -> (mstrip = w>>1, ch = w&1): owns cols [ch*128,ch*128+128) of ALL
//   3 gates -> r,z pack into coalesced u32 stores of gi_rz [TB][256][2];
//   n -> xgi [TB][256] f16.
// ---------------------------------------------------------------------------
__global__ __launch_bounds__(512) void k_encgi(const float* __restrict__ obs,
                                               const f16* __restrict__ encW_h,
                                               const float* __restrict__ enc_b,
                                               const f16* __restrict__ Wih_h,
                                               const float* __restrict__ b_ih,
                                               const float* __restrict__ b_hh,
                                               uint32_t* __restrict__ gi_rz,
                                               f16* __restrict__ xgi) {
  __shared__ __align__(16) char smem[132096];
  f16* xl = (f16*)smem;                    // 64 x 264 (stride-264) = 33792 B
  char* r2 = smem + 33792;                 // 98304 B overlay region
  // phase E layout: obsA [64][128] swizzled @ r2, encB [256][128] swizzled @ r2+16384
  // phase G layout: lB [768][64] swizzled @ r2
  const int tid = threadIdx.x, lane = tid & 63, w = tid >> 6;
  const int m0 = blockIdx.x * 64;
  const int mstrip = w >> 1, ch = w & 1;

  // ---- phase E: stage obs (f32->f16) and encW ----
#pragma unroll
  for (int i = 0; i < 4; i++) {
    int c = tid + i * 512;
    int r = c >> 5, kk = (c & 31) * 4;
    float4 v = *(const float4*)(obs + (size_t)(m0 + r) * OBS_DIM + kk);
    H2U a, b;
    a.h[0] = (f16)v.x; a.h[1] = (f16)v.y; b.h[0] = (f16)v.z; b.h[1] = (f16)v.w;
    uint32_t off = ((uint32_t)(r * 256 + kk * 2)) ^ (((uint32_t)(r & 7)) << 4);
    uint2 p; p.x = a.u; p.y = b.u;
    *(uint2*)(r2 + off) = p;
  }
#pragma unroll
  for (int i = 0; i < 8; i++) {
    int c = tid + i * 512;
    int r = c >> 4, kk = (c & 15) * 8;
    f16x8 v = *(const f16x8*)(encW_h + (size_t)r * OBS_DIM + kk);
    uint32_t off = ((uint32_t)(r * 256 + kk * 2)) ^ (((uint32_t)(r & 7)) << 4);
    *(f16x8*)(r2 + 16384 + off) = v;
  }
  __syncthreads();
  // enc GEMM: A 64x128, B(cols) 256: wave does N-half ch (8 tiles), 4 ks
  {
    f32x4 acc[8];
#pragma unroll
    for (int i = 0; i < 8; i++) acc[i] = fz4();
#pragma unroll
    for (int ks = 0; ks < 4; ks++) {
      const int ar = mstrip * 16 + (lane & 15);
      const int kofs = (ks * 32 + ((lane >> 4) << 3)) * 2;
      uint32_t aoff = ((uint32_t)(ar * 256 + kofs)) ^ (((uint32_t)(ar & 7)) << 4);
      f16x8 af = *(const f16x8*)(r2 + aoff);
#pragma unroll
      for (int i = 0; i < 8; i++) {
        const int br = ch * 128 + i * 16 + (lane & 15);
        uint32_t boff = ((uint32_t)(br * 256 + kofs)) ^ (((uint32_t)(br & 7)) << 4);
        f16x8 bfr = *(const f16x8*)(r2 + 16384 + boff);
        acc[i] = __builtin_amdgcn_mfma_f32_16x16x32_f16(af, bfr, acc[i], 0, 0, 0);
      }
    }
    // x -> LDS xl (stride 264), tanh applied
#pragma unroll
    for (int i = 0; i < 8; i++) {
      const int col = ch * 128 + i * 16 + (lane & 15);
      const float bb = enc_b[col];
#pragma unroll
      for (int r = 0; r < 4; r++) {
        const int lr = mstrip * 16 + ((lane >> 4) << 2) + r;
        xl[lr * 264 + col] = (f16)tanh_f(acc[i][r] + bb);
      }
    }
  }
  __syncthreads();  // xl ready; obsA/encB dead

  // ---- phase G: gi GEMM over K=256 in 4 chunks of 64 ----
  f32x4 acc[3][8];
#pragma unroll
  for (int g = 0; g < 3; g++)
#pragma unroll
    for (int j = 0; j < 8; j++) acc[g][j] = fz4();

  for (int kc = 0; kc < 4; kc++) {
    if (kc) __syncthreads();
#pragma unroll
    for (int i = 0; i < 12; i++) {
      int c = tid + i * 512;
      int r = c >> 3, kk = (c & 7) * 8;
      f16x8 v = *(const f16x8*)(Wih_h + (size_t)r * H_DIM + kc * 64 + kk);
      uint32_t off = ((uint32_t)(r * 128 + kk * 2)) ^ (((uint32_t)(r & 7)) << 4);
      *(f16x8*)(r2 + off) = v;
    }
    __syncthreads();
#pragma unroll
    for (int ks = 0; ks < 2; ks++) {
      const int ar = mstrip * 16 + (lane & 15);
      const int kg = kc * 64 + ks * 32 + ((lane >> 4) << 3);
      f16x8 af = *(const f16x8*)&xl[ar * 264 + kg];
      const int kofs = (ks * 32 + ((lane >> 4) << 3)) * 2;
#pragma unroll
      for (int g = 0; g < 3; g++)
#pragma unroll
        for (int j = 0; j < 8; j++) {
          const int br = g * 256 + ch * 128 + j * 16 + (lane & 15);
          uint32_t boff = ((uint32_t)(br * 128 + kofs)) ^ (((uint32_t)(br & 7)) << 4);
          f16x8 bfr = *(const f16x8*)(r2 + boff);
          acc[g][j] = __builtin_amdgcn_mfma_f32_16x16x32_f16(af, bfr, acc[g][j], 0, 0, 0);
        }
    }
  }
  // epilogue: packed u32 rz stores + f16 n stores
#pragma unroll
  for (int j = 0; j < 8; j++) {
    const int c = ch * 128 + j * 16 + (lane & 15);
    const float bbr = b_ih[c] + b_hh[c];
    const float bbz = b_ih[256 + c] + b_hh[256 + c];
    const float bbn = b_ih[512 + c];
#pragma unroll
    for (int r = 0; r < 4; r++) {
      const size_t tb = (size_t)(m0 + mstrip * 16 + ((lane >> 4) << 2) + r);
      H2U u;
      u.h[0] = (f16)(acc[0][j][r] + bbr);
      u.h[1] = (f16)(acc[1][j][r] + bbz);
      gi_rz[tb * 256 + c] = u.u;
      xgi[tb * 256 + c] = (f16)(acc[2][j][r] + bbn);
    }
  }
}

// ---------------------------------------------------------------------------
// K3: GRU scan (v5, best measured). grid(128) x block 512 (8 waves, 2/SIMD),
// WG owns 2 batch rows. W_hh: ks 0-5 in regs, ks 6-7 prebuilt B-frags in LDS.
// gi prefetched one step ahead; gh redistribution wave-local; one
// __syncthreads per step.
// ---------------------------------------------------------------------------
__global__ __launch_bounds__(512, 2) void k_scan(const float* __restrict__ Whh,
                                                 const float* __restrict__ b_hh,
                                                 const float* __restrict__ done,
                                                 const uint32_t* __restrict__ gi_rz,
                                                 f16* xgi) {
  __shared__ f16 h_l[2][16][264];      // 16.5KB double-buffered, rows 2-15 stay 0
  __shared__ float gh_l[8][6][16][2];  // 6KB [wave][g*2+hh][col&15][row]
  __shared__ float done_l[T_DIM][2];   // 4KB
  __shared__ f16 wb_l[8 * 12 * 64 * 8];  // 96KB [w][i2j][lane][8] ks 6,7 frags
  const int tid = threadIdx.x, lane = tid & 63, w = tid >> 6;
  const int b0 = blockIdx.x * 2;

  for (int i = tid; i < 2 * 16 * 264; i += 512) ((f16*)h_l)[i] = (f16)0.f;
  {
    float2 dv = *(const float2*)(done + (size_t)tid * B_DIM + b0);
    done_l[tid][0] = dv.x; done_l[tid][1] = dv.y;
  }

  // W_hh -> f16 B-frags: ks 0-5 in registers, ks 6-7 into LDS
  f16x8 wf[6][6];
#pragma unroll
  for (int g = 0; g < 3; g++) {
#pragma unroll
    for (int hh = 0; hh < 2; hh++) {
      const int i6 = g * 2 + hh;
      const int rowW = g * 256 + w * 32 + hh * 16 + (lane & 15);
      const float* wrow = Whh + (size_t)rowW * H_DIM;
#pragma unroll
      for (int ks = 0; ks < 8; ks++) {
        const int k0 = ks * 32 + ((lane >> 4) << 3);
        float4 a = *(const float4*)(wrow + k0);
        float4 b = *(const float4*)(wrow + k0 + 4);
        f16x8 f;
        f[0] = (f16)a.x; f[1] = (f16)a.y; f[2] = (f16)a.z; f[3] = (f16)a.w;
        f[4] = (f16)b.x; f[5] = (f16)b.y; f[6] = (f16)b.z; f[7] = (f16)b.w;
        if (ks < 6) wf[i6][ks] = f;
        else *(f16x8*)&wb_l[((w * 12 + i6 * 2 + (ks - 6)) * 64 + lane) * 8] = f;
      }
    }
  }
  // persistent C-in seeds: zero for r,z (bias folded in gi); bhh_n for n gate
  f32x4 zs = fz4();
  f32x4 ns0, ns1;
  {
    const float bv0 = b_hh[512 + w * 32 + (lane & 15)];
    const float bv1 = b_hh[512 + w * 32 + 16 + (lane & 15)];
    ns0[0] = bv0; ns0[1] = bv0; ns0[2] = bv0; ns0[3] = bv0;
    ns1[0] = bv1; ns1[1] = bv1; ns1[2] = bv1; ns1[3] = bv1;
  }

  const int row = lane >> 5, c = lane & 31, col = (w << 5) + c;
  const size_t base = ((size_t)b0 + row) * 256 + col;
  const uint32_t* prz = gi_rz + base;
  const f16* pgn = xgi + base;
  f16* pst = xgi + base;
  uint32_t rz_nx = *prz;
  f16 gn_nx = *pgn;
  float hreg = 0.f;

  const f16* hrd0 = &h_l[0][lane & 15][(lane >> 4) << 3];
  const f16* wrd = &wb_l[(w * 12 * 64 + lane) * 8];
  __syncthreads();

  for (int t = 0; t < T_DIM; t++) {
    const uint32_t rz_cu = rz_nx;
    const f16 gn_cu = gn_nx;
    if (t != T_DIM - 1) { prz += 65536; pgn += 65536; rz_nx = *prz; gn_nx = *pgn; }
    const int cur = t & 1;
    const f16* hrd = hrd0 + cur * (16 * 264);

    f32x4 acc[6];
    __builtin_amdgcn_s_setprio(1);
    {
      const f16x8 af0 = *(const f16x8*)&hrd[0];
      acc[0] = __builtin_amdgcn_mfma_f32_16x16x32_f16(af0, wf[0][0], zs, 0, 0, 0);
      acc[1] = __builtin_amdgcn_mfma_f32_16x16x32_f16(af0, wf[1][0], zs, 0, 0, 0);
      acc[2] = __builtin_amdgcn_mfma_f32_16x16x32_f16(af0, wf[2][0], zs, 0, 0, 0);
      acc[3] = __builtin_amdgcn_mfma_f32_16x16x32_f16(af0, wf[3][0], zs, 0, 0, 0);
      acc[4] = __builtin_amdgcn_mfma_f32_16x16x32_f16(af0, wf[4][0], ns0, 0, 0, 0);
      acc[5] = __builtin_amdgcn_mfma_f32_16x16x32_f16(af0, wf[5][0], ns1, 0, 0, 0);
    }
#pragma unroll
    for (int ks = 1; ks < 6; ks++) {
      const f16x8 af = *(const f16x8*)&hrd[ks * 32];
#pragma unroll
      for (int i = 0; i < 6; i++)
        acc[i] = __builtin_amdgcn_mfma_f32_16x16x32_f16(af, wf[i][ks], acc[i], 0, 0, 0);
    }
#pragma unroll
    for (int j = 0; j < 2; j++) {
      const f16x8 af = *(const f16x8*)&hrd[(6 + j) * 32];
#pragma unroll
      for (int i = 0; i < 6; i++) {
        const f16x8 bf = *(const f16x8*)&wrd[(i * 2 + j) * 512];
        acc[i] = __builtin_amdgcn_mfma_f32_16x16x32_f16(af, bf, acc[i], 0, 0, 0);
      }
    }
    __builtin_amdgcn_s_setprio(0);

    // wave-local gh redistribution (lanes 0-15 hold batch rows 0,1 in regs 0,1)
    if (lane < 16) {
#pragma unroll
      for (int i = 0; i < 6; i++) {
        float2 v; v.x = acc[i][0]; v.y = acc[i][1];
        *(float2*)&gh_l[w][i][lane][0] = v;
      }
    }
    __builtin_amdgcn_sched_barrier(0);
    asm volatile("s_waitcnt lgkmcnt(0)" ::: "memory");
    __builtin_amdgcn_sched_barrier(0);
    const int hh = c >> 4, cl = c & 15;
    const float ghr = gh_l[w][0 + hh][cl][row];
    const float ghz = gh_l[w][2 + hh][cl][row];
    const float ghn = gh_l[w][4 + hh][cl][row];
    H2U u; u.u = rz_cu;
    const float rr = sigm((float)u.h[0] + ghr);
    const float zz = sigm((float)u.h[1] + ghz);
    const float nn = tanh_f((float)gn_cu + rr * ghn);
    const float ho = nn + zz * (hreg - nn);
    *pst = (f16)ho; pst += 65536;                 // outs (same addr as gn slot)
    const float dn = done_l[t][row];              // masks h going into t+1
    hreg = (dn != 0.f) ? 0.f : ho;
    h_l[cur ^ 1][row][col] = (f16)hreg;
    __syncthreads();
  }
}

// ---------------------------------------------------------------------------
// K4: heads. M-tile 64, N=32 (16 pol + 1 val + pad), grid 2048, block 256.
// ---------------------------------------------------------------------------
__global__ __launch_bounds__(256) void k_heads(const f16* __restrict__ outs,
                                               const f16* __restrict__ headW_h,
                                               const float* __restrict__ pol_b,
                                               const float* __restrict__ val_b,
                                               float* __restrict__ out) {
  __shared__ f16 lA[64 * 256];  // 32KB swizzled
  __shared__ f16 lB[32 * 256];  // 16KB
  const int tid = threadIdx.x, lane = tid & 63, w = tid >> 6;
  const int m0 = blockIdx.x * 64;
#pragma unroll
  for (int i = 0; i < 8; i++) {
    int c = tid + i * 256;
    int r = c >> 5, o = (c & 31) * 8;
    f16x8 v = *(const f16x8*)(outs + (size_t)(m0 + r) * H_DIM + o);
    uint32_t off = ((uint32_t)(r * 512 + o * 2)) ^ (((uint32_t)(r & 7)) << 4);
    *(f16x8*)((char*)lA + off) = v;
  }
#pragma unroll
  for (int i = 0; i < 4; i++) {
    int c = tid + i * 256;
    int r = c >> 5, o = (c & 31) * 8;
    f16x8 v = *(const f16x8*)(headW_h + (size_t)r * H_DIM + o);
    uint32_t off = ((uint32_t)(r * 512 + o * 2)) ^ (((uint32_t)(r & 7)) << 4);
    *(f16x8*)((char*)lB + off) = v;
  }
  __syncthreads();
  f32x4 acc[2];
  acc[0] = fz4(); acc[1] = fz4();
#pragma unroll
  for (int ks = 0; ks < 8; ks++) {
    const int ar = w * 16 + (lane & 15);
    const int kofs = (ks * 32 + ((lane >> 4) << 3)) * 2;
    uint32_t aoff = ((uint32_t)(ar * 512 + kofs)) ^ (((uint32_t)(ar & 7)) << 4);
    f16x8 af = *(const f16x8*)((char*)lA + aoff);
#pragma unroll
    for (int nt = 0; nt < 2; nt++) {
      const int br = nt * 16 + (lane & 15);
      uint32_t boff = ((uint32_t)(br * 512 + kofs)) ^ (((uint32_t)(br & 7)) << 4);
      f16x8 bfr = *(const f16x8*)((char*)lB + boff);
      acc[nt] = __builtin_amdgcn_mfma_f32_16x16x32_f16(af, bfr, acc[nt], 0, 0, 0);
    }
  }
  const int n = lane & 15;
  const float pb = pol_b[n];
  const float vb = val_b[0];
#pragma unroll
  for (int r = 0; r < 4; r++) {
    const int mrow = m0 + w * 16 + ((lane >> 4) << 2) + r;
    out[(size_t)mrow * 16 + n] = acc[0][r] + pb;
    if (n == 0) out[(size_t)TB * 16 + mrow] = acc[1][r] + vb;
  }
}

// ---------------------------------------------------------------------------
// Workspace layout (192.5 MiB total):
//   [0,128Mi)        gi_rz f16 [TB][256][2]  (r,z interleaved; u32-addressable)
//   [128Mi,192Mi)    xgi  f16 [TB][256]  (gi_n -> outs, race-free)
//   [192Mi,+475KB)   encW_h | Wih_h | headW_h
// ---------------------------------------------------------------------------
extern "C" void kernel_launch(void* const* d_in, const int* in_sizes, int n_in,
                              void* d_out, int out_size, void* d_ws, size_t ws_size,
                              hipStream_t stream) {
  (void)in_sizes; (void)n_in; (void)out_size; (void)ws_size;
  const float* obs   = (const float*)d_in[0];
  const float* done  = (const float*)d_in[1];
  const float* encW  = (const float*)d_in[2];
  const float* enc_b = (const float*)d_in[3];
  const float* Wih   = (const float*)d_in[4];
  const float* Whh   = (const float*)d_in[5];
  const float* b_ih  = (const float*)d_in[6];
  const float* b_hh  = (const float*)d_in[7];
  const float* polW  = (const float*)d_in[8];
  const float* pol_b = (const float*)d_in[9];
  const float* valW  = (const float*)d_in[10];
  const float* val_b = (const float*)d_in[11];

  char* ws = (char*)d_ws;
  f16* gi_rz   = (f16*)ws;
  f16* xgi     = (f16*)(ws + (size_t)134217728);
  f16* encW_h  = (f16*)(ws + (size_t)201326592);
  f16* Wih_h   = encW_h + 32768;
  f16* headW_h = Wih_h + 196608;
  float* outp  = (float*)d_out;

  k_prep<<<dim3(928), dim3(256), 0, stream>>>(encW, Wih, polW, valW, encW_h, Wih_h, headW_h);
  k_encgi<<<dim3(2048), dim3(512), 0, stream>>>(obs, encW_h, enc_b, Wih_h, b_ih, b_hh,
                                                (uint32_t*)gi_rz, xgi);
  k_scan<<<dim3(128), dim3(512), 0, stream>>>(Whh, b_hh, done, (const uint32_t*)gi_rz, xgi);
  k_heads<<<dim3(2048), dim3(256), 0, stream>>>(xgi, headW_h, pol_b, val_b, outp);
}

// Round 11
// 770.769 us; speedup vs baseline: 1.2358x; 1.0136x over previous
//
#include <hip/hip_runtime.h>
#include <stdint.h>

#define T_DIM 512
#define B_DIM 256
#define OBS_DIM 128
#define H_DIM 256
#define TB (T_DIM * B_DIM)

typedef _Float16 f16;
typedef __attribute__((ext_vector_type(8))) _Float16 f16x8;
typedef __attribute__((ext_vector_type(4))) float f32x4;

union H2U { f16 h[2]; uint32_t u; };

__device__ __forceinline__ f32x4 fz4() { f32x4 v; v[0]=0.f; v[1]=0.f; v[2]=0.f; v[3]=0.f; return v; }
__device__ __forceinline__ float sigm(float x) {
  float e = __expf(-x);
  return __builtin_amdgcn_rcpf(1.f + e);
}
__device__ __forceinline__ float tanh_f(float x) {
  float e = __expf(-2.f * x);
  return (1.f - e) * __builtin_amdgcn_rcpf(1.f + e);
}

// ---------------------------------------------------------------------------
// K0: weights -> f16. encW 32768 | Wih 196608 | head 8192 (rows0-15 pol,16 val)
// ---------------------------------------------------------------------------
__global__ void k_prep(const float* __restrict__ encW, const float* __restrict__ Wih,
                       const float* __restrict__ polW, const float* __restrict__ valW,
                       f16* __restrict__ encW_h, f16* __restrict__ Wih_h,
                       f16* __restrict__ headW_h) {
  int e = blockIdx.x * 256 + threadIdx.x;
  if (e < 32768) { encW_h[e] = (f16)encW[e]; return; }
  e -= 32768;
  if (e < 196608) { Wih_h[e] = (f16)Wih[e]; return; }
  e -= 196608;
  if (e < 8192) {
    int r = e >> 8, c = e & 255;
    float v = (r < 16) ? polW[r * 256 + c] : (r == 16 ? valW[c] : 0.f);
    headW_h[e] = (f16)v;
  }
}

// ---------------------------------------------------------------------------
// K1: FUSED encoder + gate GEMM. grid 2048 (M-tile 64), block 512 (8 waves).
// Phase E: x-tile = tanh(obs @ enc_W^T + enc_b) computed INTO LDS (never HBM).
// Phase G: gi = x @ W_ih^T + bias, K=256 in 4 chunks.
//   wave -> (mstrip = w>>1, ch = w&1): owns cols [ch*128,ch*128+128) of ALL
//   3 gates -> r,z pack into coalesced u32 stores of gi_rz [TB][256][2];
//   n -> xgi [TB][256] f16.
// ---------------------------------------------------------------------------
__global__ __launch_bounds__(512) void k_encgi(const float* __restrict__ obs,
                                               const f16* __restrict__ encW_h,
                                               const float* __restrict__ enc_b,
                                               const f16* __restrict__ Wih_h,
                                               const float* __restrict__ b_ih,
                                               const float* __restrict__ b_hh,
                                               uint32_t* __restrict__ gi_rz,
                                               f16* __restrict__ xgi) {
  __shared__ __align__(16) char smem[132096];
  f16* xl = (f16*)smem;                    // 64 x 264 (stride-264) = 33792 B
  char* r2 = smem + 33792;                 // 98304 B overlay region
  const int tid = threadIdx.x, lane = tid & 63, w = tid >> 6;
  const int m0 = blockIdx.x * 64;
  const int mstrip = w >> 1, ch = w & 1;

  // ---- phase E: stage obs (f32->f16) and encW ----
#pragma unroll
  for (int i = 0; i < 4; i++) {
    int c = tid + i * 512;
    int r = c >> 5, kk = (c & 31) * 4;
    float4 v = *(const float4*)(obs + (size_t)(m0 + r) * OBS_DIM + kk);
    H2U a, b;
    a.h[0] = (f16)v.x; a.h[1] = (f16)v.y; b.h[0] = (f16)v.z; b.h[1] = (f16)v.w;
    uint32_t off = ((uint32_t)(r * 256 + kk * 2)) ^ (((uint32_t)(r & 7)) << 4);
    uint2 p; p.x = a.u; p.y = b.u;
    *(uint2*)(r2 + off) = p;
  }
#pragma unroll
  for (int i = 0; i < 8; i++) {
    int c = tid + i * 512;
    int r = c >> 4, kk = (c & 15) * 8;
    f16x8 v = *(const f16x8*)(encW_h + (size_t)r * OBS_DIM + kk);
    uint32_t off = ((uint32_t)(r * 256 + kk * 2)) ^ (((uint32_t)(r & 7)) << 4);
    *(f16x8*)(r2 + 16384 + off) = v;
  }
  __syncthreads();
  // enc GEMM: A 64x128, B(cols) 256: wave does N-half ch (8 tiles), 4 ks
  {
    f32x4 acc[8];
#pragma unroll
    for (int i = 0; i < 8; i++) acc[i] = fz4();
#pragma unroll
    for (int ks = 0; ks < 4; ks++) {
      const int ar = mstrip * 16 + (lane & 15);
      const int kofs = (ks * 32 + ((lane >> 4) << 3)) * 2;
      uint32_t aoff = ((uint32_t)(ar * 256 + kofs)) ^ (((uint32_t)(ar & 7)) << 4);
      f16x8 af = *(const f16x8*)(r2 + aoff);
#pragma unroll
      for (int i = 0; i < 8; i++) {
        const int br = ch * 128 + i * 16 + (lane & 15);
        uint32_t boff = ((uint32_t)(br * 256 + kofs)) ^ (((uint32_t)(br & 7)) << 4);
        f16x8 bfr = *(const f16x8*)(r2 + 16384 + boff);
        acc[i] = __builtin_amdgcn_mfma_f32_16x16x32_f16(af, bfr, acc[i], 0, 0, 0);
      }
    }
    // x -> LDS xl (stride 264), tanh applied
#pragma unroll
    for (int i = 0; i < 8; i++) {
      const int col = ch * 128 + i * 16 + (lane & 15);
      const float bb = enc_b[col];
#pragma unroll
      for (int r = 0; r < 4; r++) {
        const int lr = mstrip * 16 + ((lane >> 4) << 2) + r;
        xl[lr * 264 + col] = (f16)tanh_f(acc[i][r] + bb);
      }
    }
  }
  __syncthreads();  // xl ready; obsA/encB dead

  // ---- phase G: gi GEMM over K=256 in 4 chunks of 64 ----
  f32x4 acc[3][8];
#pragma unroll
  for (int g = 0; g < 3; g++)
#pragma unroll
    for (int j = 0; j < 8; j++) acc[g][j] = fz4();

  for (int kc = 0; kc < 4; kc++) {
    if (kc) __syncthreads();
#pragma unroll
    for (int i = 0; i < 12; i++) {
      int c = tid + i * 512;
      int r = c >> 3, kk = (c & 7) * 8;
      f16x8 v = *(const f16x8*)(Wih_h + (size_t)r * H_DIM + kc * 64 + kk);
      uint32_t off = ((uint32_t)(r * 128 + kk * 2)) ^ (((uint32_t)(r & 7)) << 4);
      *(f16x8*)(r2 + off) = v;
    }
    __syncthreads();
#pragma unroll
    for (int ks = 0; ks < 2; ks++) {
      const int ar = mstrip * 16 + (lane & 15);
      const int kg = kc * 64 + ks * 32 + ((lane >> 4) << 3);
      f16x8 af = *(const f16x8*)&xl[ar * 264 + kg];
      const int kofs = (ks * 32 + ((lane >> 4) << 3)) * 2;
#pragma unroll
      for (int g = 0; g < 3; g++)
#pragma unroll
        for (int j = 0; j < 8; j++) {
          const int br = g * 256 + ch * 128 + j * 16 + (lane & 15);
          uint32_t boff = ((uint32_t)(br * 128 + kofs)) ^ (((uint32_t)(br & 7)) << 4);
          f16x8 bfr = *(const f16x8*)(r2 + boff);
          acc[g][j] = __builtin_amdgcn_mfma_f32_16x16x32_f16(af, bfr, acc[g][j], 0, 0, 0);
        }
    }
  }
  // epilogue: packed u32 rz stores + f16 n stores
#pragma unroll
  for (int j = 0; j < 8; j++) {
    const int c = ch * 128 + j * 16 + (lane & 15);
    const float bbr = b_ih[c] + b_hh[c];
    const float bbz = b_ih[256 + c] + b_hh[256 + c];
    const float bbn = b_ih[512 + c];
#pragma unroll
    for (int r = 0; r < 4; r++) {
      const size_t tb = (size_t)(m0 + mstrip * 16 + ((lane >> 4) << 2) + r);
      H2U u;
      u.h[0] = (f16)(acc[0][j][r] + bbr);
      u.h[1] = (f16)(acc[1][j][r] + bbz);
      gi_rz[tb * 256 + c] = u.u;
      xgi[tb * 256 + c] = (f16)(acc[2][j][r] + bbn);
    }
  }
}

// ---------------------------------------------------------------------------
// K3: GRU scan (v5 structure, best measured 666-678 across 3 rounds).
// grid(128) x block 512 (8 waves, 2/SIMD), WG owns 2 batch rows. W_hh:
// ks 0-5 in regs, ks 6-7 prebuilt B-frags in LDS. gi prefetched one step
// ahead; gh redistribution wave-local; one __syncthreads per step.
// Change vs r10: #pragma unroll 2 -> compile-time h double-buffer select.
// ---------------------------------------------------------------------------
__global__ __launch_bounds__(512, 2) void k_scan(const float* __restrict__ Whh,
                                                 const float* __restrict__ b_hh,
                                                 const float* __restrict__ done,
                                                 const uint32_t* __restrict__ gi_rz,
                                                 f16* xgi) {
  __shared__ f16 h_l[2][16][264];      // 16.5KB double-buffered, rows 2-15 stay 0
  __shared__ float gh_l[8][6][16][2];  // 6KB [wave][g*2+hh][col&15][row]
  __shared__ float done_l[T_DIM][2];   // 4KB
  __shared__ f16 wb_l[8 * 12 * 64 * 8];  // 96KB [w][i2j][lane][8] ks 6,7 frags
  const int tid = threadIdx.x, lane = tid & 63, w = tid >> 6;
  const int b0 = blockIdx.x * 2;

  for (int i = tid; i < 2 * 16 * 264; i += 512) ((f16*)h_l)[i] = (f16)0.f;
  {
    float2 dv = *(const float2*)(done + (size_t)tid * B_DIM + b0);
    done_l[tid][0] = dv.x; done_l[tid][1] = dv.y;
  }

  // W_hh -> f16 B-frags: ks 0-5 in registers, ks 6-7 into LDS
  f16x8 wf[6][6];
#pragma unroll
  for (int g = 0; g < 3; g++) {
#pragma unroll
    for (int hh = 0; hh < 2; hh++) {
      const int i6 = g * 2 + hh;
      const int rowW = g * 256 + w * 32 + hh * 16 + (lane & 15);
      const float* wrow = Whh + (size_t)rowW * H_DIM;
#pragma unroll
      for (int ks = 0; ks < 8; ks++) {
        const int k0 = ks * 32 + ((lane >> 4) << 3);
        float4 a = *(const float4*)(wrow + k0);
        float4 b = *(const float4*)(wrow + k0 + 4);
        f16x8 f;
        f[0] = (f16)a.x; f[1] = (f16)a.y; f[2] = (f16)a.z; f[3] = (f16)a.w;
        f[4] = (f16)b.x; f[5] = (f16)b.y; f[6] = (f16)b.z; f[7] = (f16)b.w;
        if (ks < 6) wf[i6][ks] = f;
        else *(f16x8*)&wb_l[((w * 12 + i6 * 2 + (ks - 6)) * 64 + lane) * 8] = f;
      }
    }
  }
  // persistent C-in seeds: zero for r,z (bias folded in gi); bhh_n for n gate
  f32x4 zs = fz4();
  f32x4 ns0, ns1;
  {
    const float bv0 = b_hh[512 + w * 32 + (lane & 15)];
    const float bv1 = b_hh[512 + w * 32 + 16 + (lane & 15)];
    ns0[0] = bv0; ns0[1] = bv0; ns0[2] = bv0; ns0[3] = bv0;
    ns1[0] = bv1; ns1[1] = bv1; ns1[2] = bv1; ns1[3] = bv1;
  }

  const int row = lane >> 5, c = lane & 31, col = (w << 5) + c;
  const size_t base = ((size_t)b0 + row) * 256 + col;
  const uint32_t* prz = gi_rz + base;
  const f16* pgn = xgi + base;
  f16* pst = xgi + base;
  uint32_t rz_nx = *prz;
  f16 gn_nx = *pgn;
  float hreg = 0.f;

  const f16* hrd0 = &h_l[0][lane & 15][(lane >> 4) << 3];
  const f16* wrd = &wb_l[(w * 12 * 64 + lane) * 8];
  __syncthreads();

#pragma unroll 2
  for (int t = 0; t < T_DIM; t++) {
    const uint32_t rz_cu = rz_nx;
    const f16 gn_cu = gn_nx;
    if (t != T_DIM - 1) { prz += 65536; pgn += 65536; rz_nx = *prz; gn_nx = *pgn; }
    const int cur = t & 1;
    const f16* hrd = hrd0 + cur * (16 * 264);

    f32x4 acc[6];
    __builtin_amdgcn_s_setprio(1);
    {
      const f16x8 af0 = *(const f16x8*)&hrd[0];
      acc[0] = __builtin_amdgcn_mfma_f32_16x16x32_f16(af0, wf[0][0], zs, 0, 0, 0);
      acc[1] = __builtin_amdgcn_mfma_f32_16x16x32_f16(af0, wf[1][0], zs, 0, 0, 0);
      acc[2] = __builtin_amdgcn_mfma_f32_16x16x32_f16(af0, wf[2][0], zs, 0, 0, 0);
      acc[3] = __builtin_amdgcn_mfma_f32_16x16x32_f16(af0, wf[3][0], zs, 0, 0, 0);
      acc[4] = __builtin_amdgcn_mfma_f32_16x16x32_f16(af0, wf[4][0], ns0, 0, 0, 0);
      acc[5] = __builtin_amdgcn_mfma_f32_16x16x32_f16(af0, wf[5][0], ns1, 0, 0, 0);
    }
#pragma unroll
    for (int ks = 1; ks < 6; ks++) {
      const f16x8 af = *(const f16x8*)&hrd[ks * 32];
#pragma unroll
      for (int i = 0; i < 6; i++)
        acc[i] = __builtin_amdgcn_mfma_f32_16x16x32_f16(af, wf[i][ks], acc[i], 0, 0, 0);
    }
#pragma unroll
    for (int j = 0; j < 2; j++) {
      const f16x8 af = *(const f16x8*)&hrd[(6 + j) * 32];
#pragma unroll
      for (int i = 0; i < 6; i++) {
        const f16x8 bf = *(const f16x8*)&wrd[(i * 2 + j) * 512];
        acc[i] = __builtin_amdgcn_mfma_f32_16x16x32_f16(af, bf, acc[i], 0, 0, 0);
      }
    }
    __builtin_amdgcn_s_setprio(0);

    // wave-local gh redistribution (lanes 0-15 hold batch rows 0,1 in regs 0,1)
    if (lane < 16) {
#pragma unroll
      for (int i = 0; i < 6; i++) {
        float2 v; v.x = acc[i][0]; v.y = acc[i][1];
        *(float2*)&gh_l[w][i][lane][0] = v;
      }
    }
    __builtin_amdgcn_sched_barrier(0);
    asm volatile("s_waitcnt lgkmcnt(0)" ::: "memory");
    __builtin_amdgcn_sched_barrier(0);
    const int hh = c >> 4, cl = c & 15;
    const float ghr = gh_l[w][0 + hh][cl][row];
    const float ghz = gh_l[w][2 + hh][cl][row];
    const float ghn = gh_l[w][4 + hh][cl][row];
    H2U u; u.u = rz_cu;
    const float rr = sigm((float)u.h[0] + ghr);
    const float zz = sigm((float)u.h[1] + ghz);
    const float nn = tanh_f((float)gn_cu + rr * ghn);
    const float ho = nn + zz * (hreg - nn);
    *pst = (f16)ho; pst += 65536;                 // outs (same addr as gn slot)
    const float dn = done_l[t][row];              // masks h going into t+1
    hreg = (dn != 0.f) ? 0.f : ho;
    h_l[cur ^ 1][row][col] = (f16)hreg;
    __syncthreads();
  }
}

// ---------------------------------------------------------------------------
// K4: heads. M-tile 128, N=32 (16 pol + 1 val + pad), grid 1024, block 512.
// ---------------------------------------------------------------------------
__global__ __launch_bounds__(512) void k_heads(const f16* __restrict__ outs,
                                               const f16* __restrict__ headW_h,
                                               const float* __restrict__ pol_b,
                                               const float* __restrict__ val_b,
                                               float* __restrict__ out) {
  __shared__ f16 lA[128 * 256];  // 64KB swizzled
  __shared__ f16 lB[32 * 256];   // 16KB
  const int tid = threadIdx.x, lane = tid & 63, w = tid >> 6;
  const int m0 = blockIdx.x * 128;
#pragma unroll
  for (int i = 0; i < 8; i++) {
    int c = tid + i * 512;
    int r = c >> 5, o = (c & 31) * 8;
    f16x8 v = *(const f16x8*)(outs + (size_t)(m0 + r) * H_DIM + o);
    uint32_t off = ((uint32_t)(r * 512 + o * 2)) ^ (((uint32_t)(r & 7)) << 4);
    *(f16x8*)((char*)lA + off) = v;
  }
#pragma unroll
  for (int i = 0; i < 2; i++) {
    int c = tid + i * 512;
    int r = c >> 5, o = (c & 31) * 8;
    f16x8 v = *(const f16x8*)(headW_h + (size_t)r * H_DIM + o);
    uint32_t off = ((uint32_t)(r * 512 + o * 2)) ^ (((uint32_t)(r & 7)) << 4);
    *(f16x8*)((char*)lB + off) = v;
  }
  __syncthreads();
  f32x4 acc[2];
  acc[0] = fz4(); acc[1] = fz4();
#pragma unroll
  for (int ks = 0; ks < 8; ks++) {
    const int ar = w * 16 + (lane & 15);
    const int kofs = (ks * 32 + ((lane >> 4) << 3)) * 2;
    uint32_t aoff = ((uint32_t)(ar * 512 + kofs)) ^ (((uint32_t)(ar & 7)) << 4);
    f16x8 af = *(const f16x8*)((char*)lA + aoff);
#pragma unroll
    for (int nt = 0; nt < 2; nt++) {
      const int br = nt * 16 + (lane & 15);
      uint32_t boff = ((uint32_t)(br * 512 + kofs)) ^ (((uint32_t)(br & 7)) << 4);
      f16x8 bfr = *(const f16x8*)((char*)lB + boff);
      acc[nt] = __builtin_amdgcn_mfma_f32_16x16x32_f16(af, bfr, acc[nt], 0, 0, 0);
    }
  }
  const int n = lane & 15;
  const float pb = pol_b[n];
  const float vb = val_b[0];
#pragma unroll
  for (int r = 0; r < 4; r++) {
    const int mrow = m0 + w * 16 + ((lane >> 4) << 2) + r;
    out[(size_t)mrow * 16 + n] = acc[0][r] + pb;
    if (n == 0) out[(size_t)TB * 16 + mrow] = acc[1][r] + vb;
  }
}

// ---------------------------------------------------------------------------
// Workspace layout (192.5 MiB total):
//   [0,128Mi)        gi_rz f16 [TB][256][2]  (r,z interleaved; u32-addressable)
//   [128Mi,192Mi)    xgi  f16 [TB][256]  (gi_n -> outs, race-free)
//   [192Mi,+475KB)   encW_h | Wih_h | headW_h
// ---------------------------------------------------------------------------
extern "C" void kernel_launch(void* const* d_in, const int* in_sizes, int n_in,
                              void* d_out, int out_size, void* d_ws, size_t ws_size,
                              hipStream_t stream) {
  (void)in_sizes; (void)n_in; (void)out_size; (void)ws_size;
  const float* obs   = (const float*)d_in[0];
  const float* done  = (const float*)d_in[1];
  const float* encW  = (const float*)d_in[2];
  const float* enc_b = (const float*)d_in[3];
  const float* Wih   = (const float*)d_in[4];
  const float* Whh   = (const float*)d_in[5];
  const float* b_ih  = (const float*)d_in[6];
  const float* b_hh  = (const float*)d_in[7];
  const float* polW  = (const float*)d_in[8];
  const float* pol_b = (const float*)d_in[9];
  const float* valW  = (const float*)d_in[10];
  const float* val_b = (const float*)d_in[11];

  char* ws = (char*)d_ws;
  f16* gi_rz   = (f16*)ws;
  f16* xgi     = (f16*)(ws + (size_t)134217728);
  f16* encW_h  = (f16*)(ws + (size_t)201326592);
  f16* Wih_h   = encW_h + 32768;
  f16* headW_h = Wih_h + 196608;
  float* outp  = (float*)d_out;

  k_prep<<<dim3(928), dim3(256), 0, stream>>>(encW, Wih, polW, valW, encW_h, Wih_h, headW_h);
  k_encgi<<<dim3(2048), dim3(512), 0, stream>>>(obs, encW_h, enc_b, Wih_h, b_ih, b_hh,
                                                (uint32_t*)gi_rz, xgi);
  k_scan<<<dim3(128), dim3(512), 0, stream>>>(Whh, b_hh, done, (const uint32_t*)gi_rz, xgi);
  k_heads<<<dim3(1024), dim3(512), 0, stream>>>(xgi, headW_h, pol_b, val_b, outp);
}